// Round 12
// baseline (404.830 us; speedup 1.0000x reference)
//
#include <hip/hip_runtime.h>

typedef unsigned short u16;
typedef unsigned int u32;
typedef __attribute__((ext_vector_type(8))) short short8v;
typedef __attribute__((ext_vector_type(4))) short short4v;
typedef __attribute__((ext_vector_type(4))) float float4v;
typedef __attribute__((ext_vector_type(4))) int   int4v;

#define N_NODES 8192
#define D_IN    512
#define D_OUT   128
#define SLOPEF  0.2f
#define LOG2E   1.4426950408889634f
#define NSEG    8
#define SEGCOLS 1024   // N_NODES / NSEG
#define NCHUNK  8      // SEGCOLS / 128 (128-col chunks)
#define ROWS    128    // rows per block

static __device__ __forceinline__ u16 f2bf(float f) {
    union { float f; unsigned int i; } v; v.f = f;
    unsigned int r = v.i + 0x7fff + ((v.i >> 16) & 1);
    return (u16)(r >> 16);
}
static __device__ __forceinline__ void lds_barrier() {
    asm volatile("s_waitcnt lgkmcnt(0)" ::: "memory");
    __builtin_amdgcn_s_barrier();
    asm volatile("" ::: "memory");
}

// ---------------- Kernel C: fp32 -> bf16 convert (h -> hb row-major, W -> WbT [n][k]) --------
__global__ __launch_bounds__(256) void kc_convert(
        const float* __restrict__ h, const float* __restrict__ W,
        u16* __restrict__ hb, u16* __restrict__ WbT)
{
    if (blockIdx.x < 2048) {
        const size_t t = (size_t)blockIdx.x * 256 + threadIdx.x;
        const float4v* src = (const float4v*)h + t * 2;
        const float4v v0 = src[0], v1 = src[1];
        short8v o;
        o[0] = (short)f2bf(v0[0]); o[1] = (short)f2bf(v0[1]);
        o[2] = (short)f2bf(v0[2]); o[3] = (short)f2bf(v0[3]);
        o[4] = (short)f2bf(v1[0]); o[5] = (short)f2bf(v1[1]);
        o[6] = (short)f2bf(v1[2]); o[7] = (short)f2bf(v1[3]);
        *(short8v*)(hb + t * 8) = o;
    } else {
        const int t2 = (blockIdx.x - 2048) * 256 + threadIdx.x;
        const int k = t2 >> 4;
        const int n0 = (t2 & 15) * 8;
        const float4v* src = (const float4v*)(W + (size_t)k * D_OUT + n0);
        const float4v v0 = src[0], v1 = src[1];
        #pragma unroll
        for (int e = 0; e < 4; e++) WbT[(size_t)(n0 + e) * D_IN + k] = f2bf(v0[e]);
        #pragma unroll
        for (int e = 0; e < 4; e++) WbT[(size_t)(n0 + 4 + e) * D_IN + k] = f2bf(v1[e]);
    }
}

// ---------------- Kernel 1M: Wh = h@W via MFMA; WhT bf16 [128][8192]; f1,f2 (x log2e) --------
__global__ __launch_bounds__(256) void k1m_proj(
        const u16* __restrict__ hb, const u16* __restrict__ WbT,
        const float* __restrict__ a, u16* __restrict__ WhT,
        float* __restrict__ f1, float* __restrict__ f2)
{
    __shared__ short As[32 * 136];
    __shared__ short Ws[128 * 136];
    __shared__ float pf1[32][65];
    __shared__ float pf2[32][65];

    const int tid = threadIdx.x;
    const int rowbase = blockIdx.x * 32;
    const int lane = tid & 63, w = tid >> 6;
    const int quad = lane >> 4, m16 = lane & 15;

    float4v acc[2][2];
    #pragma unroll
    for (int mt = 0; mt < 2; mt++)
        #pragma unroll
        for (int nt = 0; nt < 2; nt++) {
            acc[mt][nt][0] = 0.f; acc[mt][nt][1] = 0.f;
            acc[mt][nt][2] = 0.f; acc[mt][nt][3] = 0.f;
        }

    for (int c = 0; c < 4; c++) {
        const int kc0 = c * 128;
        if (c) __syncthreads();
        {
            const int row = tid >> 3, koff = (tid & 7) * 16;
            const short8v* src = (const short8v*)(hb + (size_t)(rowbase + row) * D_IN + kc0 + koff);
            const short8v s0 = src[0], s1 = src[1];
            *(short8v*)&As[row * 136 + koff] = s0;
            *(short8v*)&As[row * 136 + koff + 8] = s1;
        }
        {
            const int n = tid & 127, h2 = tid >> 7;
            #pragma unroll
            for (int i = 0; i < 8; i++) {
                const int koff = h2 * 64 + i * 8;
                *(short8v*)&Ws[n * 136 + koff] =
                    *(const short8v*)(WbT + (size_t)n * D_IN + kc0 + koff);
            }
        }
        __syncthreads();
        #pragma unroll
        for (int ks = 0; ks < 4; ks++) {
            const int ko = ks * 32 + quad * 8;
            const short8v af0 = *(const short8v*)&As[m16 * 136 + ko];
            const short8v af1 = *(const short8v*)&As[(16 + m16) * 136 + ko];
            const short8v bf0 = *(const short8v*)&Ws[(w * 32 + m16) * 136 + ko];
            const short8v bf1 = *(const short8v*)&Ws[(w * 32 + 16 + m16) * 136 + ko];
            acc[0][0] = __builtin_amdgcn_mfma_f32_16x16x32_bf16(af0, bf0, acc[0][0], 0, 0, 0);
            acc[0][1] = __builtin_amdgcn_mfma_f32_16x16x32_bf16(af0, bf1, acc[0][1], 0, 0, 0);
            acc[1][0] = __builtin_amdgcn_mfma_f32_16x16x32_bf16(af1, bf0, acc[1][0], 0, 0, 0);
            acc[1][1] = __builtin_amdgcn_mfma_f32_16x16x32_bf16(af1, bf1, acc[1][1], 0, 0, 0);
        }
    }

    #pragma unroll
    for (int mt = 0; mt < 2; mt++) {
        #pragma unroll
        for (int nt = 0; nt < 2; nt++) {
            const int n = w * 32 + nt * 16 + m16;
            short4v p;
            #pragma unroll
            for (int reg = 0; reg < 4; reg++) p[reg] = (short)f2bf(acc[mt][nt][reg]);
            *(short4v*)(WhT + (size_t)n * N_NODES + rowbase + mt * 16 + quad * 4) = p;
        }
    }

    float a1v[2], a2v[2];
    #pragma unroll
    for (int nt = 0; nt < 2; nt++) {
        a1v[nt] = a[w * 32 + nt * 16 + m16];
        a2v[nt] = a[D_OUT + w * 32 + nt * 16 + m16];
    }
    #pragma unroll
    for (int mt = 0; mt < 2; mt++)
        #pragma unroll
        for (int reg = 0; reg < 4; reg++) {
            const int row = mt * 16 + quad * 4 + reg;
            pf1[row][w * 16 + m16] = acc[mt][0][reg] * a1v[0] + acc[mt][1][reg] * a1v[1];
            pf2[row][w * 16 + m16] = acc[mt][0][reg] * a2v[0] + acc[mt][1][reg] * a2v[1];
        }
    __syncthreads();
    if (tid < 32) {
        float s = 0.f;
        #pragma unroll
        for (int j = 0; j < 64; j++) s += pf1[tid][j];
        f1[rowbase + tid] = s * LOG2E;
    } else if (tid < 64) {
        float s = 0.f;
        #pragma unroll
        for (int j = 0; j < 64; j++) s += pf2[tid - 32][j];
        f2[rowbase + tid - 32] = s * LOG2E;
    }
}

// ---------------- Kernel 2: fused mask+exp2 + partial PV via MFMA ----------------
// 128 rows x 1024-col segment per block, 512 threads (8 waves), 512 blocks = 2/CU (16 waves).
// 128-col chunks, dbuf Pt, 1 barrier/chunk. Thread (r=tid>>2, g=tid&3) owns cols [g*32,+32).
// MFMA: wave w owns 16 features; acc[8] covers 128 rows.
// Rationale: WhT fragment traffic = N^2*256/ROWS -> halved vs ROWS=64; adj share 67%.
__global__ __launch_bounds__(512, 4) void k2_attn(
        const int* __restrict__ adj, const u16* __restrict__ WhT,
        const float* __restrict__ f1g, const float* __restrict__ f2g,
        float* __restrict__ numw, float* __restrict__ denw)
{
    __shared__ short Pt[2][ROWS * 136];  // 69.6 KB double-buffered P tile
    __shared__ float f2s[1152];          // 1024 + 4-float pad per 32
    __shared__ float f1s[ROWS];
    __shared__ float rs[ROWS][5];

    const int tid = threadIdx.x;
    const int rb  = blockIdx.x >> 3;
    const int seg = blockIdx.x & 7;
    const int rowbase = rb * ROWS;
    const int colbase = seg * SEGCOLS;
    const int r = tid >> 2, g = tid & 3;
    const int lane = tid & 63, w = tid >> 6;
    const int quad = lane >> 4, m16 = lane & 15;

    if (tid < ROWS) f1s[tid] = f1g[rowbase + tid];
    if (tid < 256) {
        const int idx = tid * 4;
        *(float4v*)&f2s[idx + ((idx >> 5) << 2)] = *(const float4v*)&f2g[colbase + idx];
    }

    const int4v* arow = (const int4v*)(adj + (size_t)(rowbase + r) * N_NODES + colbase);
    int4v a4[8];
    #pragma unroll
    for (int i = 0; i < 8; i++) a4[i] = arow[g * 8 + i];   // chunk 0: cols g*32..+31

    float4v acc[8];
    #pragma unroll
    for (int mt = 0; mt < 8; mt++) {
        acc[mt][0] = 0.f; acc[mt][1] = 0.f; acc[mt][2] = 0.f; acc[mt][3] = 0.f;
    }
    float ls0 = 0.f, ls1 = 0.f, ls2 = 0.f, ls3 = 0.f;

    __syncthreads();   // f1s/f2s ready

    const float f1v = f1s[r];

    auto weight_phase = [&](int jc, short* ptb) {
        const float* f2p = &f2s[jc * 144 + g * 36];
        u32 packed[16];
        #pragma unroll
        for (int i = 0; i < 8; i++) {
            const float4v fv = *(const float4v*)&f2p[i * 4];
            const int4v av = a4[i];
            u32 wb[4];
            #pragma unroll
            for (int e = 0; e < 4; e++) {
                const u32 msk = (av[e] > 0) ? 0xffff0000u : 0u;
                float x = f1v + fv[e];
                x = fmaxf(x, SLOPEF * x);                            // leaky_relu (log2 domain)
                const float ex = __builtin_amdgcn_exp2f(x);
                const u32 wt = __float_as_uint(ex) & msk;            // masked + bf16-trunc
                wb[e] = wt;
                if (e == 0) ls0 += __uint_as_float(wt);
                else if (e == 1) ls1 += __uint_as_float(wt);
                else if (e == 2) ls2 += __uint_as_float(wt);
                else ls3 += __uint_as_float(wt);
            }
            packed[i * 2]     = __builtin_amdgcn_perm(wb[1], wb[0], 0x07060302);
            packed[i * 2 + 1] = __builtin_amdgcn_perm(wb[3], wb[2], 0x07060302);
        }
        int* pdst = (int*)(ptb + r * 136 + g * 32);
        #pragma unroll
        for (int q = 0; q < 4; q++) {
            int4v st;
            st[0] = (int)packed[q * 4 + 0]; st[1] = (int)packed[q * 4 + 1];
            st[2] = (int)packed[q * 4 + 2]; st[3] = (int)packed[q * 4 + 3];
            *(int4v*)&pdst[q * 4] = st;
        }
    };

    // prologue: weight(0) into buf0, then prefetch chunk 1
    weight_phase(0, Pt[0]);
    #pragma unroll
    for (int i = 0; i < 8; i++) a4[i] = arow[32 + g * 8 + i];

    #pragma unroll 2
    for (int jc = 0; jc < NCHUNK; jc++) {
        lds_barrier();   // Pt[jc&1] complete; Pt[(jc+1)&1] free

        // ---- MFMA: acc += P[128 x 128] @ Wh[128 x 16] (this wave's 16 feature cols) ----
        {
            const u16* bp = WhT + (size_t)(w * 16 + m16) * N_NODES + colbase + jc * 128 + quad * 8;
            const short* ap = &Pt[jc & 1][m16 * 136 + quad * 8];
            #pragma unroll
            for (int ks = 0; ks < 4; ks++) {
                const int ko = ks * 32;
                const short8v bv = *(const short8v*)(bp + ko);
                #pragma unroll
                for (int mt = 0; mt < 8; mt++) {
                    const short8v af = *(const short8v*)(ap + mt * 16 * 136 + ko);
                    acc[mt] = __builtin_amdgcn_mfma_f32_16x16x32_bf16(af, bv, acc[mt], 0, 0, 0);
                }
            }
        }
        // ---- next chunk's weight phase overlaps this chunk's B-load/MFMA latency ----
        if (jc + 1 < NCHUNK) {
            weight_phase(jc + 1, Pt[(jc + 1) & 1]);
            if (jc + 2 < NCHUNK) {
                #pragma unroll
                for (int i = 0; i < 8; i++) a4[i] = arow[(jc + 2) * 32 + g * 8 + i];
            }
        }
    }

    // per-row partial denominator
    rs[r][g] = (ls0 + ls1) + (ls2 + ls3);
    __syncthreads();
    if (tid < ROWS) {
        float s = 0.f;
        #pragma unroll
        for (int j = 0; j < 4; j++) s += rs[tid][j];
        denw[(size_t)(rowbase + tid) * NSEG + seg] = s;
    }

    // epilogue: write partial numerator. C/D layout col=lane&15, row=quad*4+reg
    const int cl = w * 16 + m16;
    #pragma unroll
    for (int mt = 0; mt < 8; mt++) {
        #pragma unroll
        for (int reg = 0; reg < 4; reg++) {
            const int rl = mt * 16 + quad * 4 + reg;
            numw[((size_t)(rowbase + rl) * NSEG + seg) * D_OUT + cl] = acc[mt][reg];
        }
    }
}

// ---------------- Kernel 3: reduce partials, divide, write output ----------------
__global__ __launch_bounds__(256) void k3_reduce(
        const float* __restrict__ numw, const float* __restrict__ denw,
        float* __restrict__ out)
{
    const int tid = threadIdx.x;
    const int row = blockIdx.x * 2 + (tid >> 7);
    const int c   = tid & 127;
    float s = 0.f, d = 0.f;
    #pragma unroll
    for (int sg = 0; sg < NSEG; sg++) {
        s += numw[((size_t)row * NSEG + sg) * D_OUT + c];
        d += denw[(size_t)row * NSEG + sg];
    }
    out[(size_t)row * D_OUT + c] = s / d;
}

extern "C" void kernel_launch(void* const* d_in, const int* in_sizes, int n_in,
                              void* d_out, int out_size, void* d_ws, size_t ws_size,
                              hipStream_t stream) {
    const float* h   = (const float*)d_in[0];
    const int*   adj = (const int*)d_in[1];
    const float* W   = (const float*)d_in[2];
    const float* a   = (const float*)d_in[3];

    char* ws = (char*)d_ws;
    u16*   hb   = (u16*)ws;                                    // 8 MB
    u16*   WbT  = (u16*)(ws + (size_t)8 * 1024 * 1024);        // 128 KB
    u16*   WhT  = (u16*)(ws + (size_t)9 * 1024 * 1024);        // 2 MB
    float* f1   = (float*)(ws + (size_t)11 * 1024 * 1024);     // 32 KB
    float* f2   = f1 + N_NODES;                                // 32 KB
    float* numw = (float*)(ws + (size_t)12 * 1024 * 1024);     // 8192*8*128*4 = 32 MB
    float* denw = (float*)(ws + (size_t)44 * 1024 * 1024);     // 256 KB

    kc_convert<<<2080, 256, 0, stream>>>(h, W, hb, WbT);
    k1m_proj<<<N_NODES / 32, 256, 0, stream>>>(hb, WbT, a, WhT, f1, f2);
    k2_attn<<<(N_NODES / ROWS) * NSEG, 512, 0, stream>>>(adj, WhT, f1, f2, numw, denw);
    k3_reduce<<<N_NODES / 2, 256, 0, stream>>>(numw, denw, (float*)d_out);
}

// Round 13
// 396.688 us; speedup vs baseline: 1.0205x; 1.0205x over previous
//
#include <hip/hip_runtime.h>

typedef unsigned short u16;
typedef unsigned int u32;
typedef __attribute__((ext_vector_type(8))) short short8v;
typedef __attribute__((ext_vector_type(4))) short short4v;
typedef __attribute__((ext_vector_type(4))) float float4v;
typedef __attribute__((ext_vector_type(4))) int   int4v;

#define N_NODES 8192
#define D_IN    512
#define D_OUT   128
#define SLOPEF  0.2f
#define LOG2E   1.4426950408889634f
#define NSEG    4
#define SEGCOLS 2048   // N_NODES / NSEG
#define NCHUNK  16     // SEGCOLS / 128 (128-col chunks)
#define ROWS    64     // rows per block

static __device__ __forceinline__ u16 f2bf(float f) {
    union { float f; unsigned int i; } v; v.f = f;
    unsigned int r = v.i + 0x7fff + ((v.i >> 16) & 1);
    return (u16)(r >> 16);
}
static __device__ __forceinline__ void lds_barrier() {
    asm volatile("s_waitcnt lgkmcnt(0)" ::: "memory");
    __builtin_amdgcn_s_barrier();
    asm volatile("" ::: "memory");
}

// ---------------- Kernel C: fp32 -> bf16 convert (h -> hb row-major, W -> WbT [n][k]) --------
__global__ __launch_bounds__(256) void kc_convert(
        const float* __restrict__ h, const float* __restrict__ W,
        u16* __restrict__ hb, u16* __restrict__ WbT)
{
    if (blockIdx.x < 2048) {
        const size_t t = (size_t)blockIdx.x * 256 + threadIdx.x;
        const float4v* src = (const float4v*)h + t * 2;
        const float4v v0 = src[0], v1 = src[1];
        short8v o;
        o[0] = (short)f2bf(v0[0]); o[1] = (short)f2bf(v0[1]);
        o[2] = (short)f2bf(v0[2]); o[3] = (short)f2bf(v0[3]);
        o[4] = (short)f2bf(v1[0]); o[5] = (short)f2bf(v1[1]);
        o[6] = (short)f2bf(v1[2]); o[7] = (short)f2bf(v1[3]);
        *(short8v*)(hb + t * 8) = o;
    } else {
        const int t2 = (blockIdx.x - 2048) * 256 + threadIdx.x;
        const int k = t2 >> 4;
        const int n0 = (t2 & 15) * 8;
        const float4v* src = (const float4v*)(W + (size_t)k * D_OUT + n0);
        const float4v v0 = src[0], v1 = src[1];
        #pragma unroll
        for (int e = 0; e < 4; e++) WbT[(size_t)(n0 + e) * D_IN + k] = f2bf(v0[e]);
        #pragma unroll
        for (int e = 0; e < 4; e++) WbT[(size_t)(n0 + 4 + e) * D_IN + k] = f2bf(v1[e]);
    }
}

// ---------------- Kernel 1M: Wh = h@W via MFMA; WhT bf16 [128][8192]; f1,f2 (x log2e) --------
__global__ __launch_bounds__(256) void k1m_proj(
        const u16* __restrict__ hb, const u16* __restrict__ WbT,
        const float* __restrict__ a, u16* __restrict__ WhT,
        float* __restrict__ f1, float* __restrict__ f2)
{
    __shared__ short As[32 * 136];
    __shared__ short Ws[128 * 136];
    __shared__ float pf1[32][65];
    __shared__ float pf2[32][65];

    const int tid = threadIdx.x;
    const int rowbase = blockIdx.x * 32;
    const int lane = tid & 63, w = tid >> 6;
    const int quad = lane >> 4, m16 = lane & 15;

    float4v acc[2][2];
    #pragma unroll
    for (int mt = 0; mt < 2; mt++)
        #pragma unroll
        for (int nt = 0; nt < 2; nt++) {
            acc[mt][nt][0] = 0.f; acc[mt][nt][1] = 0.f;
            acc[mt][nt][2] = 0.f; acc[mt][nt][3] = 0.f;
        }

    for (int c = 0; c < 4; c++) {
        const int kc0 = c * 128;
        if (c) __syncthreads();
        {
            const int row = tid >> 3, koff = (tid & 7) * 16;
            const short8v* src = (const short8v*)(hb + (size_t)(rowbase + row) * D_IN + kc0 + koff);
            const short8v s0 = src[0], s1 = src[1];
            *(short8v*)&As[row * 136 + koff] = s0;
            *(short8v*)&As[row * 136 + koff + 8] = s1;
        }
        {
            const int n = tid & 127, h2 = tid >> 7;
            #pragma unroll
            for (int i = 0; i < 8; i++) {
                const int koff = h2 * 64 + i * 8;
                *(short8v*)&Ws[n * 136 + koff] =
                    *(const short8v*)(WbT + (size_t)n * D_IN + kc0 + koff);
            }
        }
        __syncthreads();
        #pragma unroll
        for (int ks = 0; ks < 4; ks++) {
            const int ko = ks * 32 + quad * 8;
            const short8v af0 = *(const short8v*)&As[m16 * 136 + ko];
            const short8v af1 = *(const short8v*)&As[(16 + m16) * 136 + ko];
            const short8v bf0 = *(const short8v*)&Ws[(w * 32 + m16) * 136 + ko];
            const short8v bf1 = *(const short8v*)&Ws[(w * 32 + 16 + m16) * 136 + ko];
            acc[0][0] = __builtin_amdgcn_mfma_f32_16x16x32_bf16(af0, bf0, acc[0][0], 0, 0, 0);
            acc[0][1] = __builtin_amdgcn_mfma_f32_16x16x32_bf16(af0, bf1, acc[0][1], 0, 0, 0);
            acc[1][0] = __builtin_amdgcn_mfma_f32_16x16x32_bf16(af1, bf0, acc[1][0], 0, 0, 0);
            acc[1][1] = __builtin_amdgcn_mfma_f32_16x16x32_bf16(af1, bf1, acc[1][1], 0, 0, 0);
        }
    }

    #pragma unroll
    for (int mt = 0; mt < 2; mt++) {
        #pragma unroll
        for (int nt = 0; nt < 2; nt++) {
            const int n = w * 32 + nt * 16 + m16;
            short4v p;
            #pragma unroll
            for (int reg = 0; reg < 4; reg++) p[reg] = (short)f2bf(acc[mt][nt][reg]);
            *(short4v*)(WhT + (size_t)n * N_NODES + rowbase + mt * 16 + quad * 4) = p;
        }
    }

    float a1v[2], a2v[2];
    #pragma unroll
    for (int nt = 0; nt < 2; nt++) {
        a1v[nt] = a[w * 32 + nt * 16 + m16];
        a2v[nt] = a[D_OUT + w * 32 + nt * 16 + m16];
    }
    #pragma unroll
    for (int mt = 0; mt < 2; mt++)
        #pragma unroll
        for (int reg = 0; reg < 4; reg++) {
            const int row = mt * 16 + quad * 4 + reg;
            pf1[row][w * 16 + m16] = acc[mt][0][reg] * a1v[0] + acc[mt][1][reg] * a1v[1];
            pf2[row][w * 16 + m16] = acc[mt][0][reg] * a2v[0] + acc[mt][1][reg] * a2v[1];
        }
    __syncthreads();
    if (tid < 32) {
        float s = 0.f;
        #pragma unroll
        for (int j = 0; j < 64; j++) s += pf1[tid][j];
        f1[rowbase + tid] = s * LOG2E;
    } else if (tid < 64) {
        float s = 0.f;
        #pragma unroll
        for (int j = 0; j < 64; j++) s += pf2[tid - 32][j];
        f2[rowbase + tid - 32] = s * LOG2E;
    }
}

// ---------------- Kernel 2: fused mask+exp2 + partial PV via MFMA ----------------
// 64 rows x 2048-col segment per block (512 blocks). 128-col chunks, dbuf Pt, 1 barrier/chunk.
// Thread (r,g): r=tid>>2 in [0,64), g=tid&3 owns cols [g*32, g*32+32) of each chunk.
// Best measured config (R11): adj/WhT request mix 50/50, 256-thread blocks.
__global__ __launch_bounds__(256, 2) void k2_attn(
        const int* __restrict__ adj, const u16* __restrict__ WhT,
        const float* __restrict__ f1g, const float* __restrict__ f2g,
        float* __restrict__ numw, float* __restrict__ denw)
{
    __shared__ short Pt[2][ROWS * 136];  // 34.8 KB double-buffered P tile (stride 136 shorts)
    __shared__ float f2s[2304];          // 2048 + 4-float pad per 32 (bank-spread)
    __shared__ float f1s[ROWS];
    __shared__ float rs[ROWS][5];
    __shared__ float ssum[ROWS];

    const int tid = threadIdx.x;
    const int rb  = blockIdx.x >> 2;
    const int seg = blockIdx.x & 3;
    const int rowbase = rb * ROWS;
    const int colbase = seg * SEGCOLS;
    const int r = tid >> 2, g = tid & 3;
    const int lane = tid & 63, w = tid >> 6;
    const int quad = lane >> 4, m16 = lane & 15;

    if (tid < ROWS) f1s[tid] = f1g[rowbase + tid];
    #pragma unroll
    for (int i = 0; i < 2; i++) {
        const int idx = (tid + 256 * i) * 4;
        *(float4v*)&f2s[idx + ((idx >> 5) << 2)] = *(const float4v*)&f2g[colbase + idx];
    }

    const int4v* arow = (const int4v*)(adj + (size_t)(rowbase + r) * N_NODES + colbase);
    int4v a4[8];
    #pragma unroll
    for (int i = 0; i < 8; i++) a4[i] = arow[g * 8 + i];   // chunk 0: cols g*32..+31

    float4v acc[4][2];
    #pragma unroll
    for (int mt = 0; mt < 4; mt++)
        #pragma unroll
        for (int nt = 0; nt < 2; nt++) {
            acc[mt][nt][0] = 0.f; acc[mt][nt][1] = 0.f;
            acc[mt][nt][2] = 0.f; acc[mt][nt][3] = 0.f;
        }
    float ls0 = 0.f, ls1 = 0.f, ls2 = 0.f, ls3 = 0.f;

    __syncthreads();   // f1s/f2s ready

    const float f1v = f1s[r];

    auto weight_phase = [&](int jc, short* ptb) {
        const float* f2p = &f2s[jc * 144 + g * 36];
        u32 packed[16];
        #pragma unroll
        for (int i = 0; i < 8; i++) {
            const float4v fv = *(const float4v*)&f2p[i * 4];
            const int4v av = a4[i];
            u32 wb[4];
            #pragma unroll
            for (int e = 0; e < 4; e++) {
                const u32 msk = (av[e] > 0) ? 0xffff0000u : 0u;
                float x = f1v + fv[e];
                x = fmaxf(x, SLOPEF * x);                            // leaky_relu (log2 domain)
                const float ex = __builtin_amdgcn_exp2f(x);
                const u32 wt = __float_as_uint(ex) & msk;            // masked + bf16-trunc
                wb[e] = wt;
                if (e == 0) ls0 += __uint_as_float(wt);
                else if (e == 1) ls1 += __uint_as_float(wt);
                else if (e == 2) ls2 += __uint_as_float(wt);
                else ls3 += __uint_as_float(wt);
            }
            packed[i * 2]     = __builtin_amdgcn_perm(wb[1], wb[0], 0x07060302);
            packed[i * 2 + 1] = __builtin_amdgcn_perm(wb[3], wb[2], 0x07060302);
        }
        int* pdst = (int*)(ptb + r * 136 + g * 32);
        #pragma unroll
        for (int q = 0; q < 4; q++) {
            int4v st;
            st[0] = (int)packed[q * 4 + 0]; st[1] = (int)packed[q * 4 + 1];
            st[2] = (int)packed[q * 4 + 2]; st[3] = (int)packed[q * 4 + 3];
            *(int4v*)&pdst[q * 4] = st;
        }
    };

    // prologue: weight(0) into buf0, then prefetch chunk 1
    weight_phase(0, Pt[0]);
    #pragma unroll
    for (int i = 0; i < 8; i++) a4[i] = arow[32 + g * 8 + i];

    #pragma unroll 2
    for (int jc = 0; jc < NCHUNK; jc++) {
        lds_barrier();   // Pt[jc&1] complete; Pt[(jc+1)&1] free

        // ---- MFMA: acc += P[64 x 128] @ Wh[128 x 128] (this wave's 32 feature cols) ----
        {
            const u16* b0p = WhT + (size_t)(w * 32 + m16) * N_NODES + colbase + jc * 128 + quad * 8;
            const u16* b1p = b0p + 16 * N_NODES;
            const short* ap = &Pt[jc & 1][m16 * 136 + quad * 8];
            #pragma unroll
            for (int ks = 0; ks < 4; ks++) {
                const int ko = ks * 32;
                const short8v bv0 = *(const short8v*)(b0p + ko);
                const short8v bv1 = *(const short8v*)(b1p + ko);
                #pragma unroll
                for (int mt = 0; mt < 4; mt++) {
                    const short8v af = *(const short8v*)(ap + mt * 16 * 136 + ko);
                    acc[mt][0] = __builtin_amdgcn_mfma_f32_16x16x32_bf16(af, bv0, acc[mt][0], 0, 0, 0);
                    acc[mt][1] = __builtin_amdgcn_mfma_f32_16x16x32_bf16(af, bv1, acc[mt][1], 0, 0, 0);
                }
            }
        }
        // ---- next chunk's weight phase overlaps this chunk's B-load/MFMA latency ----
        if (jc + 1 < NCHUNK) {
            weight_phase(jc + 1, Pt[(jc + 1) & 1]);
            if (jc + 2 < NCHUNK) {
                #pragma unroll
                for (int i = 0; i < 8; i++) a4[i] = arow[(jc + 2) * 32 + g * 8 + i];
            }
        }
    }

    // per-row partial denominator
    rs[r][g] = (ls0 + ls1) + (ls2 + ls3);
    __syncthreads();
    if (tid < ROWS) {
        float s = 0.f;
        #pragma unroll
        for (int j = 0; j < 4; j++) s += rs[tid][j];
        ssum[tid] = s;
        denw[(size_t)(rowbase + tid) * NSEG + seg] = s;
    }
    __syncthreads();

    // epilogue: write partial numerator. C/D layout col=lane&15, row=quad*4+reg
    #pragma unroll
    for (int mt = 0; mt < 4; mt++) {
        #pragma unroll
        for (int nt = 0; nt < 2; nt++) {
            const int cl = w * 32 + nt * 16 + m16;
            #pragma unroll
            for (int reg = 0; reg < 4; reg++) {
                const int rl = mt * 16 + quad * 4 + reg;
                numw[((size_t)(rowbase + rl) * NSEG + seg) * D_OUT + cl] = acc[mt][nt][reg];
            }
        }
    }
}

// ---------------- Kernel 3: reduce partials, divide, write output ----------------
__global__ __launch_bounds__(256) void k3_reduce(
        const float* __restrict__ numw, const float* __restrict__ denw,
        float* __restrict__ out)
{
    const int tid = threadIdx.x;
    const int row = blockIdx.x * 2 + (tid >> 7);
    const int c   = tid & 127;
    float s = 0.f, d = 0.f;
    #pragma unroll
    for (int sg = 0; sg < NSEG; sg++) {
        s += numw[((size_t)row * NSEG + sg) * D_OUT + c];
        d += denw[(size_t)row * NSEG + sg];
    }
    out[(size_t)row * D_OUT + c] = s / d;
}

extern "C" void kernel_launch(void* const* d_in, const int* in_sizes, int n_in,
                              void* d_out, int out_size, void* d_ws, size_t ws_size,
                              hipStream_t stream) {
    const float* h   = (const float*)d_in[0];
    const int*   adj = (const int*)d_in[1];
    const float* W   = (const float*)d_in[2];
    const float* a   = (const float*)d_in[3];

    char* ws = (char*)d_ws;
    u16*   hb   = (u16*)ws;                                    // 8 MB
    u16*   WbT  = (u16*)(ws + (size_t)8 * 1024 * 1024);        // 128 KB
    u16*   WhT  = (u16*)(ws + (size_t)9 * 1024 * 1024);        // 2 MB
    float* f1   = (float*)(ws + (size_t)11 * 1024 * 1024);     // 32 KB
    float* f2   = f1 + N_NODES;                                // 32 KB
    float* numw = (float*)(ws + (size_t)12 * 1024 * 1024);     // 16 MB
    float* denw = (float*)(ws + (size_t)28 * 1024 * 1024);     // 128 KB

    kc_convert<<<2080, 256, 0, stream>>>(h, W, hb, WbT);
    k1m_proj<<<N_NODES / 32, 256, 0, stream>>>(hb, WbT, a, WhT, f1, f2);
    k2_attn<<<(N_NODES / ROWS) * NSEG, 256, 0, stream>>>(adj, WhT, f1, f2, numw, denw);
    k3_reduce<<<N_NODES / 2, 256, 0, stream>>>(numw, denw, (float*)d_out);
}